// Round 2
// baseline (121.012 us; speedup 1.0000x reference)
//
#include <hip/hip_runtime.h>
#include <cmath>

#define D_MODEL 1792
#define BB      256
#define II      2048          // inner dim
#define FOURI   8192

__device__ __forceinline__ float sigm(float v) { return 1.0f / (1.0f + expf(-v)); }

__device__ __forceinline__ float waveReduce(float s) {
    #pragma unroll
    for (int off = 32; off > 0; off >>= 1) s += __shfl_down(s, off, 64);
    return s;
}

// dot of one 2048-wide weight row with concat(x_t[1792], y_t[256])
__device__ __forceinline__ float dotConcat(const float* __restrict__ wrow,
                                           const float* __restrict__ xt,
                                           const float* __restrict__ yt,
                                           int lane) {
    float sum = 0.f;
    #pragma unroll
    for (int p = 0; p < 8; ++p) {
        const int j = p * 256 + lane * 4;
        float4 w = *(const float4*)(wrow + j);
        float4 v = (p < 7) ? *(const float4*)(xt + j)
                           : *(const float4*)(yt + (j - D_MODEL));
        sum += w.x * v.x + w.y * v.y + w.z * v.z + w.w * v.w;
    }
    return sum;
}

// dot of one 2048-wide weight row with a contiguous 2048 vector (h)
__device__ __forceinline__ float dotH(const float* __restrict__ wrow,
                                      const float* __restrict__ h,
                                      int lane) {
    float sum = 0.f;
    #pragma unroll
    for (int p = 0; p < 8; ++p) {
        const int j = p * 256 + lane * 4;
        float4 w = *(const float4*)(wrow + j);
        float4 v = *(const float4*)(h + j);
        sum += w.x * v.x + w.y * v.y + w.z * v.z + w.w * v.w;
    }
    return sum;
}

// ---------------------------------------------------------------------------
// K0: blocks 0..2047   -> step-0 cell (h0=c0=0, so gates = ih + biases only),
//                         block r computes all 4 gate dots -> h0[r], c0[r].
//     blocks 2048..4095-> precompute gih[1] rows for step 1.
// ---------------------------------------------------------------------------
__global__ __launch_bounds__(256) void step0_kernel(
    const float* __restrict__ x,     // (6,1792)
    const float* __restrict__ y,     // (5,256)
    const float* __restrict__ Wih5,  // (5,8192,2048)
    const float* __restrict__ bih5,  // (5,8192)
    const float* __restrict__ bhh5,  // (5,8192)
    float* __restrict__ h_out,       // (2048)
    float* __restrict__ c_out,       // (2048)
    float* __restrict__ gih_out)     // (8192) for step 1
{
    const int wave = threadIdx.x >> 6;
    const int lane = threadIdx.x & 63;

    if (blockIdx.x < 2048) {
        __shared__ float partial[4];
        const int r = blockIdx.x;
        const float* wrow = Wih5 + ((size_t)wave * II + r) * (size_t)II;
        float sum = dotConcat(wrow, x, y, lane);
        sum = waveReduce(sum);
        if (lane == 0)
            partial[wave] = sum + bih5[wave * II + r] + bhh5[wave * II + r];
        __syncthreads();
        if (threadIdx.x == 0) {
            const float gi = partial[0], gg = partial[2], go = partial[3];
            const float cc = sigm(gi) * tanhf(gg);      // f*c0 = 0
            c_out[r] = cc;
            h_out[r] = sigm(go) * tanhf(cc);
        }
    } else {
        const int u = blockIdx.x - 2048;
        const float* wrow = Wih5 + ((size_t)FOURI + (size_t)wave * II + u) * (size_t)II;
        float sum = dotConcat(wrow, x + D_MODEL, y + BB, lane);
        sum = waveReduce(sum);
        if (lane == 0)
            gih_out[wave * II + u] =
                sum + bih5[FOURI + wave * II + u] + bhh5[FOURI + wave * II + u];
    }
}

// ---------------------------------------------------------------------------
// K1..K3: blocks 0..2047    -> recurrent cell for step t (hh dots + gih_in),
//         blocks 2048..4095 -> precompute gih for step t+1.
// ---------------------------------------------------------------------------
__global__ __launch_bounds__(256) void mid_kernel(
    const float* __restrict__ Whh,     // (8192,2048) step t
    const float* __restrict__ gih_in,  // (8192) step t
    const float* __restrict__ h_in,    // (2048)
    float* __restrict__ h_out,         // (2048)
    float* __restrict__ c,             // (2048) in place
    const float* __restrict__ WihN,    // (8192,2048) step t+1
    const float* __restrict__ bihN,    // (8192)
    const float* __restrict__ bhhN,    // (8192)
    const float* __restrict__ xN,      // (1792)
    const float* __restrict__ yN,      // (256)
    float* __restrict__ gih_out)       // (8192) step t+1
{
    const int wave = threadIdx.x >> 6;
    const int lane = threadIdx.x & 63;

    if (blockIdx.x < 2048) {
        __shared__ float partial[4];
        const int r = blockIdx.x;
        const float* wrow = Whh + ((size_t)wave * II + r) * (size_t)II;
        float sum = dotH(wrow, h_in, lane);
        sum = waveReduce(sum);
        if (lane == 0) partial[wave] = sum + gih_in[wave * II + r];
        __syncthreads();
        if (threadIdx.x == 0) {
            const float gi = partial[0], gf = partial[1], gg = partial[2], go = partial[3];
            const float cc = sigm(gf) * c[r] + sigm(gi) * tanhf(gg);
            c[r] = cc;
            h_out[r] = sigm(go) * tanhf(cc);
        }
    } else {
        const int u = blockIdx.x - 2048;
        const float* wrow = WihN + ((size_t)wave * II + u) * (size_t)II;
        float sum = dotConcat(wrow, xN, yN, lane);
        sum = waveReduce(sum);
        if (lane == 0)
            gih_out[wave * II + u] = sum + bihN[wave * II + u] + bhhN[wave * II + u];
    }
}

// ---------------------------------------------------------------------------
// K4: blocks 0..2047   -> recurrent cell step 4,
//     blocks 2048..2303-> ih dots for FINAL cell (only rows q*2048+1792+u,
//                         u in [0,256)) over x[5] (1792 cols). Compact store.
// ---------------------------------------------------------------------------
__global__ __launch_bounds__(256) void mid4_kernel(
    const float* __restrict__ Whh,     // (8192,2048) step 4
    const float* __restrict__ gih_in,  // (8192)
    const float* __restrict__ h_in,    // (2048)
    float* __restrict__ h_out,         // (2048)
    float* __restrict__ c,             // (2048) in place
    const float* __restrict__ WihF,    // (8192,1792)
    const float* __restrict__ bihF,    // (8192)
    const float* __restrict__ bhhF,    // (8192)
    const float* __restrict__ x5,      // (1792)
    float* __restrict__ gihF_out)      // (1024) compact [gate][256]
{
    const int wave = threadIdx.x >> 6;
    const int lane = threadIdx.x & 63;

    if (blockIdx.x < 2048) {
        __shared__ float partial[4];
        const int r = blockIdx.x;
        const float* wrow = Whh + ((size_t)wave * II + r) * (size_t)II;
        float sum = dotH(wrow, h_in, lane);
        sum = waveReduce(sum);
        if (lane == 0) partial[wave] = sum + gih_in[wave * II + r];
        __syncthreads();
        if (threadIdx.x == 0) {
            const float gi = partial[0], gf = partial[1], gg = partial[2], go = partial[3];
            const float cc = sigm(gf) * c[r] + sigm(gi) * tanhf(gg);
            c[r] = cc;
            h_out[r] = sigm(go) * tanhf(cc);
        }
    } else {
        const int u = blockIdx.x - 2048;            // [0,256)
        const int r = wave * II + D_MODEL + u;      // row in (8192,1792)
        const float* wrow = WihF + (size_t)r * (size_t)D_MODEL;
        float sum = 0.f;
        #pragma unroll
        for (int p = 0; p < 7; ++p) {
            const int j = p * 256 + lane * 4;
            float4 w = *(const float4*)(wrow + j);
            float4 v = *(const float4*)(x5 + j);
            sum += w.x * v.x + w.y * v.y + w.z * v.z + w.w * v.w;
        }
        sum = waveReduce(sum);
        if (lane == 0)
            gihF_out[wave * BB + u] = sum + bihF[r] + bhhF[r];
    }
}

// ---------------------------------------------------------------------------
// K5: final cell, only h-rows 1792..2047 (output h[-256:]).
// ---------------------------------------------------------------------------
__global__ __launch_bounds__(256) void final_kernel(
    const float* __restrict__ WhhF,   // (8192,2048)
    const float* __restrict__ gihF,   // (1024) compact [gate][256]
    const float* __restrict__ h_in,   // (2048)
    const float* __restrict__ c,      // (2048)
    float* __restrict__ out)          // (256)
{
    __shared__ float partial[4];
    const int k    = blockIdx.x;        // [0,256)
    const int r    = D_MODEL + k;
    const int wave = threadIdx.x >> 6;
    const int lane = threadIdx.x & 63;

    const float* wrow = WhhF + ((size_t)wave * II + r) * (size_t)II;
    float sum = dotH(wrow, h_in, lane);
    sum = waveReduce(sum);
    if (lane == 0) partial[wave] = sum + gihF[wave * BB + k];
    __syncthreads();
    if (threadIdx.x == 0) {
        const float gi = partial[0], gf = partial[1], gg = partial[2], go = partial[3];
        const float cc = sigm(gf) * c[r] + sigm(gi) * tanhf(gg);
        out[k] = sigm(go) * tanhf(cc);
    }
}

extern "C" void kernel_launch(void* const* d_in, const int* in_sizes, int n_in,
                              void* d_out, int out_size, void* d_ws, size_t ws_size,
                              hipStream_t stream) {
    const float* x    = (const float*)d_in[0];
    const float* y    = (const float*)d_in[1];
    const float* Wih5 = (const float*)d_in[2];
    const float* Whh5 = (const float*)d_in[3];
    const float* bih5 = (const float*)d_in[4];
    const float* bhh5 = (const float*)d_in[5];
    const float* WihF = (const float*)d_in[6];
    const float* WhhF = (const float*)d_in[7];
    const float* bihF = (const float*)d_in[8];
    const float* bhhF = (const float*)d_in[9];
    float* out = (float*)d_out;

    float* ws   = (float*)d_ws;
    float* gihA = ws;                  // 8192
    float* gihB = gihA + FOURI;        // 8192
    float* gihF = gihB + FOURI;        // 1024
    float* hA   = gihF + 1024;         // 2048
    float* hB   = hA + II;             // 2048
    float* cbuf = hB + II;             // 2048

    const size_t WOFF = (size_t)FOURI * II;   // per-step weight matrix stride

    // K0: step-0 cell + gih[1]
    step0_kernel<<<4096, 256, 0, stream>>>(x, y, Wih5, bih5, bhh5, hA, cbuf, gihA);

    // K1: step 1 (consumes gihA) + gih[2] -> gihB
    mid_kernel<<<4096, 256, 0, stream>>>(
        Whh5 + 1 * WOFF, gihA, hA, hB, cbuf,
        Wih5 + 2 * WOFF, bih5 + 2 * FOURI, bhh5 + 2 * FOURI,
        x + 2 * D_MODEL, y + 2 * BB, gihB);

    // K2: step 2 (gihB) + gih[3] -> gihA
    mid_kernel<<<4096, 256, 0, stream>>>(
        Whh5 + 2 * WOFF, gihB, hB, hA, cbuf,
        Wih5 + 3 * WOFF, bih5 + 3 * FOURI, bhh5 + 3 * FOURI,
        x + 3 * D_MODEL, y + 3 * BB, gihA);

    // K3: step 3 (gihA) + gih[4] -> gihB
    mid_kernel<<<4096, 256, 0, stream>>>(
        Whh5 + 3 * WOFF, gihA, hA, hB, cbuf,
        Wih5 + 4 * WOFF, bih5 + 4 * FOURI, bhh5 + 4 * FOURI,
        x + 4 * D_MODEL, y + 4 * BB, gihB);

    // K4: step 4 (gihB) + final-cell ih (partial rows) -> gihF
    mid4_kernel<<<2304, 256, 0, stream>>>(
        Whh5 + 4 * WOFF, gihB, hB, hA, cbuf,
        WihF, bihF, bhhF, x + 5 * D_MODEL, gihF);

    // K5: final cell -> out
    final_kernel<<<BB, 256, 0, stream>>>(WhhF, gihF, hA, cbuf, out);
}